// Round 18
// baseline (187.305 us; speedup 1.0000x reference)
//
#include <hip/hip_runtime.h>

typedef __bf16 bf16x8 __attribute__((ext_vector_type(8)));
typedef __bf16 bf16x4 __attribute__((ext_vector_type(4)));
typedef float f32x4 __attribute__((ext_vector_type(4)));

#define LSEQ 8192
#define DDIM 64
#define QS 256
#define CHUNK 128
#define VOCAB 1027
#define RELK_ELEMS (VOCAB * DDIM)        // 65728
#define RELVT_PITCH 768
#define RELVT_ELEMS (DDIM * RELVT_PITCH) // 49152
#define SMAX 10.0f                       // static softmax max (log2 units)
#define QSCALE 0.18033688011112042f     // 0.125 * log2(e)

#define WS_RELK_OFF 0
#define WS_RELVT_OFF 131456
#define WS_KIMG_OFF 229888
#define WS_VIMG_OFF (WS_KIMG_OFF + 16777216)
#define WS_NEED ((size_t)WS_VIMG_OFF + 16777216)

__device__ __forceinline__ int swze(int row) { return ((row ^ (row >> 3)) & 7) << 3; }

__device__ __forceinline__ f32x4 mfma16(bf16x8 a, bf16x8 b, f32x4 c) {
  return __builtin_amdgcn_mfma_f32_16x16x32_bf16(a, b, c, 0, 0, 0);
}

__device__ __forceinline__ float fexp2(float x) { return __builtin_exp2f(x); }

__device__ __forceinline__ void gload16(const __bf16* g, __bf16* l) {
  __builtin_amdgcn_global_load_lds(
      (const __attribute__((address_space(1))) void*)g,
      (__attribute__((address_space(3))) void*)l, 16, 0, 0);
}

__device__ __forceinline__ bf16x8 cvt8(float4 a, float4 b, float sc) {
  bf16x8 r;
  r[0] = (__bf16)(a.x * sc); r[1] = (__bf16)(a.y * sc);
  r[2] = (__bf16)(a.z * sc); r[3] = (__bf16)(a.w * sc);
  r[4] = (__bf16)(b.x * sc); r[5] = (__bf16)(b.y * sc);
  r[6] = (__bf16)(b.z * sc); r[7] = (__bf16)(b.w * sc);
  return r;
}

__global__ void prep_rel(const float* __restrict__ rk, const float* __restrict__ rv,
                         __bf16* __restrict__ relk, __bf16* __restrict__ relvT) {
  int i = blockIdx.x * 256 + threadIdx.x;
  if (i < RELK_ELEMS) relk[i] = (__bf16)rk[i];
  if (i < RELVT_ELEMS) {
    int d = i / RELVT_PITCH, j = i - d * RELVT_PITCH;
    relvT[i] = (__bf16)rv[(j + 2) * DDIM + d];
  }
}

// K tile image: per (bh*64+tile) a 16KB block whose linear 16B-block b holds
// K[tile*128 + (b>>3)][ (((b&7)*8) ^ swze(b>>3)) .. +8 ] as bf16.
__global__ void prep_kimg(const float* __restrict__ k, __bf16* __restrict__ kimg) {
  int i = blockIdx.x * 256 + threadIdx.x;  // [0, 16*64*1024)
  int b = i & 1023;
  int bt = i >> 10;  // bh*64 + tile
  int y = b >> 3;
  int d0 = ((b & 7) * 8) ^ swze(y);
  const float* src = k + ((size_t)bt * 128 + y) * DDIM + d0;
  float4 a = *(const float4*)src;
  float4 bb = *(const float4*)(src + 4);
  *(bf16x8*)(kimg + (size_t)i * 8) = cvt8(a, bb, 1.0f);
}

// V^T tile image: linear 16B-block b holds vT[d=b>>4][ (((b&15)*8)^swze(d)) .. +8 ].
__global__ void prep_vimg(const float* __restrict__ v, __bf16* __restrict__ vimg) {
  __shared__ __align__(16) __bf16 t[CHUNK * DDIM];
  const int bt = blockIdx.x;  // bh*64 + tile
  const int tid = threadIdx.x;
  const float* vb = v + (size_t)bt * CHUNK * DDIM;
#pragma unroll
  for (int rep = 0; rep < 4; ++rep) {
    int e = (rep * 256 + tid) * 8;
    float4 a = *(const float4*)(vb + e);
    float4 b = *(const float4*)(vb + e + 4);
    *(bf16x8*)&t[e] = cvt8(a, b, 1.0f);
  }
  __syncthreads();
#pragma unroll
  for (int rep = 0; rep < 4; ++rep) {
    int b = rep * 256 + tid;
    int d = b >> 4;
    int y0 = ((b & 15) * 8) ^ swze(d);
    bf16x8 o8;
#pragma unroll
    for (int j = 0; j < 8; ++j) o8[j] = t[(y0 + j) * DDIM + d];
    *(bf16x8*)(vimg + (size_t)bt * 8192 + (size_t)b * 8) = o8;
  }
}

// One WG = 128 q-rows, 8 waves x 16 rows (r15 per-wave body), window 512 in
// four 128-chunks. One kbuf/vbuf stage serves 8 waves -> staging+barrier cost
// per q-row halves; LDS 72.5KB -> 2 blocks/CU = 16 waves/CU (2x TLP of r15).
template <bool PRECONV>
__global__ __launch_bounds__(512, 2) void attn_kernel(
    const float* __restrict__ qg, const float* __restrict__ kg, const float* __restrict__ vg,
    const __bf16* __restrict__ relk, const __bf16* __restrict__ relvT,
    const __bf16* __restrict__ kimg, const __bf16* __restrict__ vimg,
    float* __restrict__ outg) {
  __shared__ __align__(16) __bf16 kbuf[CHUNK * DDIM];   // 16KB K [y][d] swizzled
  __shared__ __align__(16) __bf16 vbuf[CHUNK * DDIM];   // 16KB vT [d][y] swizzled
  __shared__ __align__(16) __bf16 pbuf[128 * CHUNK];    // 32KB P [q][y], per-wave slabs
  __shared__ __bf16 ring[8][2][16][17];                 // 8.5KB per-wave QR^T ring

  const int phys = blockIdx.x;
  const int xcd = phys & 7;
  const int mseq = phys >> 3;       // [0,128)
  const int p = mseq & 1;           // which 128-row half of the 256-block
  const int gl = mseq >> 1;         // [0,64)
  const int pair = xcd * 64 + gl;   // [0,512)
  const int bh = pair >> 5;
  const int nblk = pair & 31;

  const int tid = threadIdx.x;
  const int w = tid >> 6;           // [0,8)
  const int lane = tid & 63;
  const int c16 = lane & 15;
  const int grp = lane >> 4;

  const int row_base = 128 * p + 16 * w;  // {0,...,240}
  const int rb16 = 8 * p + w;
  const int c0w = 194 - row_base;
  const int j0w = 192 - row_base;
  const int prow = 16 * w + c16;          // [0,128)

  const int cstart = (nblk == 0) ? 2 : 0;
  const int c_hi = 3 + p;                 // WG-uniform: all p=0 waves inactive at c=3

  auto stage_k = [&](int c) {
    if constexpr (PRECONV) {
      const __bf16* base = kimg + (((size_t)bh * 64 + (size_t)(2 * nblk - 2 + c)) << 13);
      const int boff = 128 * w;
#pragma unroll
      for (int rep = 0; rep < 2; ++rep)
        gload16(base + (size_t)(boff + 64 * rep + lane) * 8, &kbuf[(boff + 64 * rep) * 8]);
    } else {
      const int ty = tid >> 3, td = tid & 7, d0 = td * 8;  // ty in [0,64)
      const float* kb = kg + ((size_t)bh * LSEQ + (size_t)(2 * nblk - 2 + c) * CHUNK) * DDIM;
#pragma unroll
      for (int rep = 0; rep < 2; ++rep) {
        int yc = ty + rep * 64;
        const float4* sp = (const float4*)(kb + yc * DDIM + d0);
        *(bf16x8*)&kbuf[yc * 64 + (d0 ^ swze(yc))] = cvt8(sp[0], sp[1], 1.0f);
      }
    }
  };
  auto stage_v = [&](int c) {
    if constexpr (PRECONV) {
      const __bf16* base = vimg + (((size_t)bh * 64 + (size_t)(2 * nblk - 2 + c)) << 13);
      const int boff = 128 * w;
#pragma unroll
      for (int rep = 0; rep < 2; ++rep)
        gload16(base + (size_t)(boff + 64 * rep + lane) * 8, &vbuf[(boff + 64 * rep) * 8]);
    } else {
      const int ty = tid >> 3, td = tid & 7, d0 = td * 8;
      const float* vb = vg + ((size_t)bh * LSEQ + (size_t)(2 * nblk - 2 + c) * CHUNK) * DDIM;
#pragma unroll
      for (int rep = 0; rep < 2; ++rep) {
        int yc = ty + rep * 64;
        const float4* sp = (const float4*)(vb + yc * DDIM + d0);
        float ff[8] = {sp[0].x, sp[0].y, sp[0].z, sp[0].w, sp[1].x, sp[1].y, sp[1].z, sp[1].w};
#pragma unroll
        for (int i = 0; i < 8; ++i) {
          int d = d0 + i;
          vbuf[d * CHUNK + (yc ^ swze(d))] = (__bf16)ff[i];
        }
      }
    }
  };

  // q fragment: Q[q=row_base+c16][d=32*kk+8*grp+i], scaled by D^-0.5 * log2(e)
  bf16x8 qa[2];
  {
    const float* qrow = qg + (size_t)(bh * LSEQ + nblk * QS + row_base + c16) * DDIM;
#pragma unroll
    for (int kk = 0; kk < 2; ++kk) {
      const float4* sp = (const float4*)(qrow + kk * 32 + grp * 8);
      qa[kk] = cvt8(sp[0], sp[1], QSCALE);
    }
  }

  f32x4 o[4];  // o[jd][r] = O[q=4*grp+r][d=16*jd+c16]
#pragma unroll
  for (int jd = 0; jd < 4; ++jd) o[jd] = f32x4{0.f, 0.f, 0.f, 0.f};
  float lsum = 0.f;

  // QR^T tile with immediate ring write (prologue only)
  auto qr_tile = [&](int ju) {
    f32x4 acc = {0.f, 0.f, 0.f, 0.f};
    int t = c0w + 16 * ju + c16;
    const bf16x8* b0 = (const bf16x8*)(relk + t * DDIM + 8 * grp);
    const bf16x8* b1 = (const bf16x8*)(relk + t * DDIM + 32 + 8 * grp);
    acc = mfma16(*b0, qa[0], acc);
    acc = mfma16(*b1, qa[1], acc);
#pragma unroll
    for (int r = 0; r < 4; ++r) ring[w][ju & 1][4 * grp + r][c16] = (__bf16)acc[r];
  };

  stage_k(cstart);
  __syncthreads();  // kbuf(cstart) resident

  for (int c = cstart; c < c_hi; ++c) {
    int jtl_hi = rb16 + 17 - 8 * c;     // wave-uniform valid-tile bound
    jtl_hi = jtl_hi < 0 ? 0 : (jtl_hi > 8 ? 8 : jtl_hi);
    const bool active = jtl_hi > 0;

    stage_v(c);  // async into vbuf; hidden under QK

    if (active) {
      if (c == cstart) {  // later chunks inherit 8c+3/8c+4 from chunk c-1's jtl 6/7
        qr_tile(8 * c + 3);
        qr_tile(8 * c + 4);
      }
      float ps = 0.f;
#pragma unroll
      for (int jtl = 0; jtl < 8; ++jtl) {
        if (jtl < jtl_hi) {  // wave-uniform: skip fully-masked tail tiles
          const int jt = 8 * c + jtl;
          // phase 1: QR tile jt+5 into registers (ring write deferred)
          f32x4 qacc = {0.f, 0.f, 0.f, 0.f};
          {
            int t = c0w + 16 * (jt + 5) + c16;
            const bf16x8* b0 = (const bf16x8*)(relk + t * DDIM + 8 * grp);
            const bf16x8* b1 = (const bf16x8*)(relk + t * DDIM + 32 + 8 * grp);
            qacc = mfma16(*b0, qa[0], qacc);
            qacc = mfma16(*b1, qa[1], qacc);
          }
          // phase 2: QK
          f32x4 acc = {-SMAX, -SMAX, -SMAX, -SMAX};
          int krow = 16 * jtl + c16;
          const bf16x8 aK0 = *(const bf16x8*)&kbuf[krow * 64 + ((8 * grp) ^ swze(krow))];
          const bf16x8 aK1 = *(const bf16x8*)&kbuf[krow * 64 + ((32 + 8 * grp) ^ swze(krow))];
          acc = mfma16(aK0, qa[0], acc);
          acc = mfma16(aK1, qa[1], acc);
          // phase 3: ring reads (tiles jt+3/jt+4, written >=1 jtl ago) + exp + P store
          bf16x4 pw;
#pragma unroll
          for (int r = 0; r < 4; ++r) {
            int sk = 4 * grp + r + 15 - c16;
            float qrv = (float)ring[w][(jt + 3 + (sk >> 4)) & 1][sk & 15][c16];
            int yv = 16 * jt + 4 * grp + r;
            float arg = (yv <= row_base + c16 + 256) ? (acc[r] + qrv) : -1e9f;
            float pv = fexp2(arg);
            ps += pv;
            pw[r] = (__bf16)pv;
          }
          *(bf16x4*)&pbuf[prow * CHUNK + ((16 * jtl + 4 * grp) ^ swze(prow))] = pw;
          // phase 4: deferred ring write of jt+5
#pragma unroll
          for (int r = 0; r < 4; ++r) ring[w][(jt + 5) & 1][4 * grp + r][c16] = (__bf16)qacc[r];
        }
      }
      // odd jtl_hi -> PV's ks block [jtl_hi-1, jtl_hi] reads P tile jtl_hi,
      // which the guarded loop no longer writes. Zero-fill that one tile.
      if (jtl_hi < 8 && (jtl_hi & 1)) {
        bf16x4 z = {};
        *(bf16x4*)&pbuf[prow * CHUNK + ((16 * jtl_hi + 4 * grp) ^ swze(prow))] = z;
      }
      lsum += ps;
    }

    __syncthreads();  // vbuf(c) resident; kbuf reads done

    if (c + 1 < c_hi) stage_k(c + 1);  // async into kbuf; hidden under PV

    if (active) {
      const int ks_hi = (jtl_hi + 1) >> 1;          // P tiles beyond are never read
      int s2_hi = (16 * jtl_hi + 62) >> 5;
      s2_hi = s2_hi > 5 ? 5 : s2_hi;
      const int ylim = 16 * jtl_hi;                  // <= CHUNK
      __builtin_amdgcn_s_setprio(1);
#pragma unroll
      for (int ks = 0; ks < 4; ++ks) {
        if (ks < ks_hi) {
          bf16x8 aP = *(const bf16x8*)&pbuf[prow * CHUNK + ((32 * ks + 8 * grp) ^ swze(prow))];
#pragma unroll
          for (int jd = 0; jd < 4; ++jd) {
            int drow = 16 * jd + c16;
            bf16x8 bV = *(const bf16x8*)&vbuf[drow * CHUNK + ((32 * ks + 8 * grp) ^ swze(drow))];
            o[jd] = mfma16(aP, bV, o[jd]);
          }
        }
      }
#pragma unroll
      for (int s2 = 0; s2 < 5; ++s2) {
        if (s2 < s2_hi) {
          bf16x8 aW;
#pragma unroll
          for (int i = 0; i < 8; ++i) {
            int yl = 32 * s2 + 8 * grp + i + c16 - 31;
            __bf16 pv = (__bf16)0.f;
            if (yl >= 0 && yl < ylim) pv = pbuf[prow * CHUNK + (yl ^ swze(prow))];
            aW[i] = pv;
          }
          const int u0 = 128 * c + 32 + 32 * s2 + 8 * grp;
#pragma unroll
          for (int jd = 0; jd < 4; ++jd) {
            int d = 16 * jd + c16;
            const bf16x8* bR = (const bf16x8*)(relvT + d * RELVT_PITCH + j0w + u0);
            o[jd] = mfma16(aW, *bR, o[jd]);
          }
        }
      }
      __builtin_amdgcn_s_setprio(0);
    }

    __syncthreads();  // own K(c+1) drained; vbuf/pbuf reads done
  }

  // ---- epilogue: lsum reduce, normalize, store ----
  lsum += __shfl_xor(lsum, 16);
  lsum += __shfl_xor(lsum, 32);
  float inv = 1.0f / lsum;  // lane c16 holds q-row c16's inverse sum
  float* ob = outg + (size_t)(bh * LSEQ + nblk * QS + row_base) * DDIM;
#pragma unroll
  for (int r = 0; r < 4; ++r) {
    float ir = __shfl(inv, 4 * grp + r);
#pragma unroll
    for (int jd = 0; jd < 4; ++jd) {
      ob[(4 * grp + r) * DDIM + 16 * jd + c16] = o[jd][r] * ir;
    }
  }
}

extern "C" void kernel_launch(void* const* d_in, const int* in_sizes, int n_in,
                              void* d_out, int out_size, void* d_ws, size_t ws_size,
                              hipStream_t stream) {
  const float* q = (const float*)d_in[0];
  const float* k = (const float*)d_in[1];
  const float* v = (const float*)d_in[2];
  const float* rk = (const float*)d_in[3];
  const float* rv = (const float*)d_in[4];

  char* ws = (char*)d_ws;
  __bf16* relk = (__bf16*)(ws + WS_RELK_OFF);
  __bf16* relvT = (__bf16*)(ws + WS_RELVT_OFF);
  __bf16* kimg = (__bf16*)(ws + WS_KIMG_OFF);
  __bf16* vimg = (__bf16*)(ws + WS_VIMG_OFF);

  prep_rel<<<257, 256, 0, stream>>>(rk, rv, relk, relvT);
  if (ws_size >= WS_NEED) {
    prep_kimg<<<4096, 256, 0, stream>>>(k, kimg);
    prep_vimg<<<1024, 256, 0, stream>>>(v, vimg);
    attn_kernel<true><<<1024, 512, 0, stream>>>(q, k, v, relk, relvT, kimg, vimg, (float*)d_out);
  } else {
    attn_kernel<false><<<1024, 512, 0, stream>>>(q, k, v, relk, relvT, relk, relk, (float*)d_out);
  }
}

// Round 19
// 180.587 us; speedup vs baseline: 1.0372x; 1.0372x over previous
//
#include <hip/hip_runtime.h>

typedef __bf16 bf16x8 __attribute__((ext_vector_type(8)));
typedef __bf16 bf16x4 __attribute__((ext_vector_type(4)));
typedef float f32x4 __attribute__((ext_vector_type(4)));

#define LSEQ 8192
#define DDIM 64
#define QS 256
#define CHUNK 128
#define VOCAB 1027
#define RELK_ELEMS (VOCAB * DDIM)        // 65728
#define RELVT_PITCH 768
#define RELVT_ELEMS (DDIM * RELVT_PITCH) // 49152
#define SMAX 10.0f                       // static softmax max (log2 units)
#define QSCALE 0.18033688011112042f     // 0.125 * log2(e)

#define WS_RELK_OFF 0
#define WS_RELVT_OFF 131456
#define WS_KIMG_OFF 229888
#define WS_VIMG_OFF (WS_KIMG_OFF + 16777216)
#define WS_NEED ((size_t)WS_VIMG_OFF + 16777216)

__device__ __forceinline__ int swze(int row) { return ((row ^ (row >> 3)) & 7) << 3; }

__device__ __forceinline__ f32x4 mfma16(bf16x8 a, bf16x8 b, f32x4 c) {
  return __builtin_amdgcn_mfma_f32_16x16x32_bf16(a, b, c, 0, 0, 0);
}

__device__ __forceinline__ float fexp2(float x) { return __builtin_exp2f(x); }

__device__ __forceinline__ void gload16(const __bf16* g, __bf16* l) {
  __builtin_amdgcn_global_load_lds(
      (const __attribute__((address_space(1))) void*)g,
      (__attribute__((address_space(3))) void*)l, 16, 0, 0);
}

__device__ __forceinline__ bf16x8 cvt8(float4 a, float4 b, float sc) {
  bf16x8 r;
  r[0] = (__bf16)(a.x * sc); r[1] = (__bf16)(a.y * sc);
  r[2] = (__bf16)(a.z * sc); r[3] = (__bf16)(a.w * sc);
  r[4] = (__bf16)(b.x * sc); r[5] = (__bf16)(b.y * sc);
  r[6] = (__bf16)(b.z * sc); r[7] = (__bf16)(b.w * sc);
  return r;
}

// Merged prep: blocks [0,257) rel tables; [257,4353) K tile image; [4353,5377) V^T image.
__global__ void prep_all(const float* __restrict__ rk, const float* __restrict__ rv,
                         const float* __restrict__ k, const float* __restrict__ v,
                         __bf16* __restrict__ relk, __bf16* __restrict__ relvT,
                         __bf16* __restrict__ kimg, __bf16* __restrict__ vimg) {
  __shared__ __align__(16) __bf16 t[CHUNK * DDIM];  // used by vimg part only
  const int bid = blockIdx.x;
  const int tid = threadIdx.x;
  if (bid < 257) {
    int i = bid * 256 + tid;
    if (i < RELK_ELEMS) relk[i] = (__bf16)rk[i];
    if (i < RELVT_ELEMS) {
      int d = i / RELVT_PITCH, j = i - d * RELVT_PITCH;
      relvT[i] = (__bf16)rv[(j + 2) * DDIM + d];
    }
  } else if (bid < 257 + 4096) {
    // K tile image: 16B-block b holds K[tile*128+(b>>3)][(((b&7)*8)^swze(b>>3))..+8]
    int i = (bid - 257) * 256 + tid;  // [0, 16*64*1024)
    int b = i & 1023;
    int bt = i >> 10;  // bh*64 + tile
    int y = b >> 3;
    int d0 = ((b & 7) * 8) ^ swze(y);
    const float* src = k + ((size_t)bt * 128 + y) * DDIM + d0;
    float4 a = *(const float4*)src;
    float4 bb = *(const float4*)(src + 4);
    *(bf16x8*)(kimg + (size_t)i * 8) = cvt8(a, bb, 1.0f);
  } else {
    // V^T tile image: 16B-block b holds vT[d=b>>4][(((b&15)*8)^swze(d))..+8]
    const int bt = bid - (257 + 4096);  // bh*64 + tile
    const float* vb = v + (size_t)bt * CHUNK * DDIM;
#pragma unroll
    for (int rep = 0; rep < 4; ++rep) {
      int e = (rep * 256 + tid) * 8;
      float4 a = *(const float4*)(vb + e);
      float4 b = *(const float4*)(vb + e + 4);
      *(bf16x8*)&t[e] = cvt8(a, b, 1.0f);
    }
    __syncthreads();
#pragma unroll
    for (int rep = 0; rep < 4; ++rep) {
      int b = rep * 256 + tid;
      int d = b >> 4;
      int y0 = ((b & 15) * 8) ^ swze(d);
      bf16x8 o8;
#pragma unroll
      for (int j = 0; j < 8; ++j) o8[j] = t[(y0 + j) * DDIM + d];
      *(bf16x8*)(vimg + (size_t)bt * 8192 + (size_t)b * 8) = o8;
    }
  }
}

// One WG = 64 q-rows, 4 waves x 16 rows, window 512 in four 128-chunks.
// r15 body verbatim (best measured: 167.7us attn, zero spill): async
// global_load_lds staging from pre-swizzled images, 2 barriers/chunk,
// deferred-ring QR pipeline, wave-uniform tail guards + odd-jtl_hi P zero-fill.
template <bool PRECONV>
__global__ __launch_bounds__(256, 2) void attn_kernel(
    const float* __restrict__ qg, const float* __restrict__ kg, const float* __restrict__ vg,
    const __bf16* __restrict__ relk, const __bf16* __restrict__ relvT,
    const __bf16* __restrict__ kimg, const __bf16* __restrict__ vimg,
    float* __restrict__ outg) {
  __shared__ __align__(16) __bf16 kbuf[CHUNK * DDIM];  // 16KB K [y][d] swizzled
  __shared__ __align__(16) __bf16 vbuf[CHUNK * DDIM];  // 16KB vT [d][y] swizzled
  __shared__ __align__(16) __bf16 pbuf[64 * CHUNK];    // 16KB P [q][y], per-wave slabs
  __shared__ __bf16 ring[4][2][16][17];                // 4.25KB per-wave QR^T ring (bf16)

  const int phys = blockIdx.x;
  const int xcd = phys & 7;
  const int mseq = phys >> 3;
  const int rg = mseq & 3;
  const int gl = mseq >> 2;
  const int pair = xcd * 64 + gl;
  const int bh = pair >> 5;
  const int nblk = pair & 31;

  const int tid = threadIdx.x;
  const int w = tid >> 6;
  const int lane = tid & 63;
  const int c16 = lane & 15;
  const int grp = lane >> 4;

  const int row_base = rg * 64 + 16 * w;
  const int c0w = 194 - row_base;
  const int j0w = 192 - row_base;
  const int prow = 16 * w + c16;

  const int cstart = (nblk == 0) ? 2 : 0;
  const int c_hi = (rg >= 2) ? 4 : 3;

  auto stage_k = [&](int c) {
    if constexpr (PRECONV) {
      const __bf16* base = kimg + (((size_t)bh * 64 + (size_t)(2 * nblk - 2 + c)) << 13);
      const int boff = 256 * w;
#pragma unroll
      for (int rep = 0; rep < 4; ++rep)
        gload16(base + (size_t)(boff + 64 * rep + lane) * 8, &kbuf[(boff + 64 * rep) * 8]);
    } else {
      const int ty = tid >> 3, td = tid & 7, d0 = td * 8;
      const float* kb = kg + ((size_t)bh * LSEQ + (size_t)(2 * nblk - 2 + c) * CHUNK) * DDIM;
#pragma unroll
      for (int rep = 0; rep < 4; ++rep) {
        int yc = ty + rep * 32;
        const float4* sp = (const float4*)(kb + yc * DDIM + d0);
        *(bf16x8*)&kbuf[yc * 64 + (d0 ^ swze(yc))] = cvt8(sp[0], sp[1], 1.0f);
      }
    }
  };
  auto stage_v = [&](int c) {
    if constexpr (PRECONV) {
      const __bf16* base = vimg + (((size_t)bh * 64 + (size_t)(2 * nblk - 2 + c)) << 13);
      const int boff = 256 * w;
#pragma unroll
      for (int rep = 0; rep < 4; ++rep)
        gload16(base + (size_t)(boff + 64 * rep + lane) * 8, &vbuf[(boff + 64 * rep) * 8]);
    } else {
      const int ty = tid >> 3, td = tid & 7, d0 = td * 8;
      const float* vb = vg + ((size_t)bh * LSEQ + (size_t)(2 * nblk - 2 + c) * CHUNK) * DDIM;
#pragma unroll
      for (int rep = 0; rep < 4; ++rep) {
        int yc = ty + rep * 32;
        const float4* sp = (const float4*)(vb + yc * DDIM + d0);
        float ff[8] = {sp[0].x, sp[0].y, sp[0].z, sp[0].w, sp[1].x, sp[1].y, sp[1].z, sp[1].w};
#pragma unroll
        for (int i = 0; i < 8; ++i) {
          int d = d0 + i;
          vbuf[d * CHUNK + (yc ^ swze(d))] = (__bf16)ff[i];
        }
      }
    }
  };

  // q fragment: Q[q=row_base+c16][d=32*kk+8*grp+i], scaled by D^-0.5 * log2(e)
  bf16x8 qa[2];
  {
    const float* qrow = qg + (size_t)(bh * LSEQ + nblk * QS + row_base + c16) * DDIM;
#pragma unroll
    for (int kk = 0; kk < 2; ++kk) {
      const float4* sp = (const float4*)(qrow + kk * 32 + grp * 8);
      qa[kk] = cvt8(sp[0], sp[1], QSCALE);
    }
  }

  f32x4 o[4];  // o[jd][r] = O[q=4*grp+r][d=16*jd+c16]
#pragma unroll
  for (int jd = 0; jd < 4; ++jd) o[jd] = f32x4{0.f, 0.f, 0.f, 0.f};
  float lsum = 0.f;

  // QR^T tile with immediate ring write (prologue only)
  auto qr_tile = [&](int ju) {
    f32x4 acc = {0.f, 0.f, 0.f, 0.f};
    int t = c0w + 16 * ju + c16;
    const bf16x8* b0 = (const bf16x8*)(relk + t * DDIM + 8 * grp);
    const bf16x8* b1 = (const bf16x8*)(relk + t * DDIM + 32 + 8 * grp);
    acc = mfma16(*b0, qa[0], acc);
    acc = mfma16(*b1, qa[1], acc);
#pragma unroll
    for (int r = 0; r < 4; ++r) ring[w][ju & 1][4 * grp + r][c16] = (__bf16)acc[r];
  };

  stage_k(cstart);
  __syncthreads();  // kbuf(cstart) resident

  for (int c = cstart; c < c_hi; ++c) {
    int jtl_hi = 4 * rg + w + 17 - 8 * c;     // wave-uniform valid-tile bound
    jtl_hi = jtl_hi < 0 ? 0 : (jtl_hi > 8 ? 8 : jtl_hi);
    const bool active = jtl_hi > 0;

    stage_v(c);  // async into vbuf; hidden under QK

    if (active) {
      if (c == cstart) {  // later chunks inherit 8c+3/8c+4 from chunk c-1's jtl 6/7
        qr_tile(8 * c + 3);
        qr_tile(8 * c + 4);
      }
      float ps = 0.f;
#pragma unroll
      for (int jtl = 0; jtl < 8; ++jtl) {
        if (jtl < jtl_hi) {  // wave-uniform: skip fully-masked tail tiles
          const int jt = 8 * c + jtl;
          // phase 1: QR tile jt+5 into registers (ring write deferred)
          f32x4 qacc = {0.f, 0.f, 0.f, 0.f};
          {
            int t = c0w + 16 * (jt + 5) + c16;
            const bf16x8* b0 = (const bf16x8*)(relk + t * DDIM + 8 * grp);
            const bf16x8* b1 = (const bf16x8*)(relk + t * DDIM + 32 + 8 * grp);
            qacc = mfma16(*b0, qa[0], qacc);
            qacc = mfma16(*b1, qa[1], qacc);
          }
          // phase 2: QK
          f32x4 acc = {-SMAX, -SMAX, -SMAX, -SMAX};
          int krow = 16 * jtl + c16;
          const bf16x8 aK0 = *(const bf16x8*)&kbuf[krow * 64 + ((8 * grp) ^ swze(krow))];
          const bf16x8 aK1 = *(const bf16x8*)&kbuf[krow * 64 + ((32 + 8 * grp) ^ swze(krow))];
          acc = mfma16(aK0, qa[0], acc);
          acc = mfma16(aK1, qa[1], acc);
          // phase 3: ring reads (tiles jt+3/jt+4, written >=1 jtl ago) + exp + P store
          bf16x4 pw;
#pragma unroll
          for (int r = 0; r < 4; ++r) {
            int sk = 4 * grp + r + 15 - c16;
            float qrv = (float)ring[w][(jt + 3 + (sk >> 4)) & 1][sk & 15][c16];
            int yv = 16 * jt + 4 * grp + r;
            float arg = (yv <= row_base + c16 + 256) ? (acc[r] + qrv) : -1e9f;
            float pv = fexp2(arg);
            ps += pv;
            pw[r] = (__bf16)pv;
          }
          *(bf16x4*)&pbuf[prow * CHUNK + ((16 * jtl + 4 * grp) ^ swze(prow))] = pw;
          // phase 4: deferred ring write of jt+5
#pragma unroll
          for (int r = 0; r < 4; ++r) ring[w][(jt + 5) & 1][4 * grp + r][c16] = (__bf16)qacc[r];
        }
      }
      // odd jtl_hi -> PV's ks block [jtl_hi-1, jtl_hi] reads P tile jtl_hi,
      // which the guarded loop no longer writes. Zero-fill that one tile.
      if (jtl_hi < 8 && (jtl_hi & 1)) {
        bf16x4 z = {};
        *(bf16x4*)&pbuf[prow * CHUNK + ((16 * jtl_hi + 4 * grp) ^ swze(prow))] = z;
      }
      lsum += ps;
    }

    __syncthreads();  // vbuf(c) resident; kbuf reads done

    if (c + 1 < c_hi) stage_k(c + 1);  // async into kbuf; hidden under PV

    if (active) {
      const int ks_hi = (jtl_hi + 1) >> 1;          // P tiles beyond are never read
      int s2_hi = (16 * jtl_hi + 62) >> 5;
      s2_hi = s2_hi > 5 ? 5 : s2_hi;
      const int ylim = 16 * jtl_hi;                  // <= CHUNK
      __builtin_amdgcn_s_setprio(1);
#pragma unroll
      for (int ks = 0; ks < 4; ++ks) {
        if (ks < ks_hi) {
          bf16x8 aP = *(const bf16x8*)&pbuf[prow * CHUNK + ((32 * ks + 8 * grp) ^ swze(prow))];
#pragma unroll
          for (int jd = 0; jd < 4; ++jd) {
            int drow = 16 * jd + c16;
            bf16x8 bV = *(const bf16x8*)&vbuf[drow * CHUNK + ((32 * ks + 8 * grp) ^ swze(drow))];
            o[jd] = mfma16(aP, bV, o[jd]);
          }
        }
      }
#pragma unroll
      for (int s2 = 0; s2 < 5; ++s2) {
        if (s2 < s2_hi) {
          bf16x8 aW;
#pragma unroll
          for (int i = 0; i < 8; ++i) {
            int yl = 32 * s2 + 8 * grp + i + c16 - 31;
            __bf16 pv = (__bf16)0.f;
            if (yl >= 0 && yl < ylim) pv = pbuf[prow * CHUNK + (yl ^ swze(prow))];
            aW[i] = pv;
          }
          const int u0 = 128 * c + 32 + 32 * s2 + 8 * grp;
#pragma unroll
          for (int jd = 0; jd < 4; ++jd) {
            int d = 16 * jd + c16;
            const bf16x8* bR = (const bf16x8*)(relvT + d * RELVT_PITCH + j0w + u0);
            o[jd] = mfma16(aW, *bR, o[jd]);
          }
        }
      }
      __builtin_amdgcn_s_setprio(0);
    }

    __syncthreads();  // own K(c+1) drained; vbuf/pbuf reads done
  }

  // ---- epilogue: lsum reduce, normalize, store ----
  lsum += __shfl_xor(lsum, 16);
  lsum += __shfl_xor(lsum, 32);
  float inv = 1.0f / lsum;  // lane c16 holds q-row c16's inverse sum
  float* ob = outg + (size_t)(bh * LSEQ + nblk * QS + row_base) * DDIM;
#pragma unroll
  for (int r = 0; r < 4; ++r) {
    float ir = __shfl(inv, 4 * grp + r);
#pragma unroll
    for (int jd = 0; jd < 4; ++jd) {
      ob[(4 * grp + r) * DDIM + 16 * jd + c16] = o[jd][r] * ir;
    }
  }
}

extern "C" void kernel_launch(void* const* d_in, const int* in_sizes, int n_in,
                              void* d_out, int out_size, void* d_ws, size_t ws_size,
                              hipStream_t stream) {
  const float* q = (const float*)d_in[0];
  const float* k = (const float*)d_in[1];
  const float* v = (const float*)d_in[2];
  const float* rk = (const float*)d_in[3];
  const float* rv = (const float*)d_in[4];

  char* ws = (char*)d_ws;
  __bf16* relk = (__bf16*)(ws + WS_RELK_OFF);
  __bf16* relvT = (__bf16*)(ws + WS_RELVT_OFF);
  __bf16* kimg = (__bf16*)(ws + WS_KIMG_OFF);
  __bf16* vimg = (__bf16*)(ws + WS_VIMG_OFF);

  if (ws_size >= WS_NEED) {
    prep_all<<<257 + 4096 + 1024, 256, 0, stream>>>(rk, rv, k, v, relk, relvT, kimg, vimg);
    attn_kernel<true><<<2048, 256, 0, stream>>>(q, k, v, relk, relvT, kimg, vimg, (float*)d_out);
  } else {
    prep_all<<<257, 256, 0, stream>>>(rk, rv, k, v, relk, relvT, relk, relk);  // rel tables only
    attn_kernel<false><<<2048, 256, 0, stream>>>(q, k, v, relk, relvT, relk, relk, (float*)d_out);
  }
}

// Round 20
// 172.400 us; speedup vs baseline: 1.0865x; 1.0475x over previous
//
#include <hip/hip_runtime.h>

typedef __bf16 bf16x8 __attribute__((ext_vector_type(8)));
typedef __bf16 bf16x4 __attribute__((ext_vector_type(4)));
typedef float f32x4 __attribute__((ext_vector_type(4)));

#define LSEQ 8192
#define DDIM 64
#define QS 256
#define CHUNK 128
#define VOCAB 1027
#define RELK_ELEMS (VOCAB * DDIM)        // 65728
#define RELVT_PITCH 768
#define RELVT_ELEMS (DDIM * RELVT_PITCH) // 49152
#define SMAX 10.0f                       // static softmax max (log2 units)
#define QSCALE 0.18033688011112042f     // 0.125 * log2(e)

#define WS_RELK_OFF 0
#define WS_RELVT_OFF 131456
#define WS_RELK2_OFF 229888
#define WS_KIMG_OFF (WS_RELK2_OFF + 131456)
#define WS_VIMG_OFF (WS_KIMG_OFF + 16777216)
#define WS_NEED ((size_t)WS_VIMG_OFF + 16777216)

__device__ __forceinline__ int swze(int row) { return ((row ^ (row >> 3)) & 7) << 3; }

__device__ __forceinline__ f32x4 mfma16(bf16x8 a, bf16x8 b, f32x4 c) {
  return __builtin_amdgcn_mfma_f32_16x16x32_bf16(a, b, c, 0, 0, 0);
}

__device__ __forceinline__ float fexp2(float x) { return __builtin_exp2f(x); }

__device__ __forceinline__ void gload16(const __bf16* g, __bf16* l) {
  __builtin_amdgcn_global_load_lds(
      (const __attribute__((address_space(1))) void*)g,
      (__attribute__((address_space(3))) void*)l, 16, 0, 0);
}

__device__ __forceinline__ bf16x8 cvt8(float4 a, float4 b, float sc) {
  bf16x8 r;
  r[0] = (__bf16)(a.x * sc); r[1] = (__bf16)(a.y * sc);
  r[2] = (__bf16)(a.z * sc); r[3] = (__bf16)(a.w * sc);
  r[4] = (__bf16)(b.x * sc); r[5] = (__bf16)(b.y * sc);
  r[6] = (__bf16)(b.z * sc); r[7] = (__bf16)(b.w * sc);
  return r;
}

// Merged prep: [0,257) rel tables; [257,514) relk2 (row-swizzled relk image);
// [514,4610) K tile image; [4610,5634) V^T tile image.
__global__ void prep_all(const float* __restrict__ rk, const float* __restrict__ rv,
                         const float* __restrict__ k, const float* __restrict__ v,
                         __bf16* __restrict__ relk, __bf16* __restrict__ relvT,
                         __bf16* __restrict__ relk2,
                         __bf16* __restrict__ kimg, __bf16* __restrict__ vimg) {
  __shared__ __align__(16) __bf16 t[CHUNK * DDIM];  // used by vimg part only
  const int bid = blockIdx.x;
  const int tid = threadIdx.x;
  if (bid < 257) {
    int i = bid * 256 + tid;
    if (i < RELK_ELEMS) relk[i] = (__bf16)rk[i];
    if (i < RELVT_ELEMS) {
      int d = i / RELVT_PITCH, j = i - d * RELVT_PITCH;
      relvT[i] = (__bf16)rv[(j + 2) * DDIM + d];
    }
  } else if (bid < 514) {
    // relk2[g][sc] = relk[g][sc ^ swze((g-2)&63)]: linear gload16 into rbuf local
    // row l then lands pre-swizzled, since staged base B == 2 (mod 64) => l == g-2 (mod 64).
    int i = (bid - 257) * 256 + tid;
    if (i < RELK_ELEMS) {
      int g = i >> 6, sc = i & 63;
      relk2[i] = (__bf16)rk[g * DDIM + (sc ^ swze((g - 2) & 63))];
    }
  } else if (bid < 514 + 4096) {
    // K tile image: 16B-block b holds K[tile*128+(b>>3)][(((b&7)*8)^swze(b>>3))..+8]
    int i = (bid - 514) * 256 + tid;  // [0, 16*64*1024)
    int b = i & 1023;
    int bt = i >> 10;  // bh*64 + tile
    int y = b >> 3;
    int d0 = ((b & 7) * 8) ^ swze(y);
    const float* src = k + ((size_t)bt * 128 + y) * DDIM + d0;
    float4 a = *(const float4*)src;
    float4 bb = *(const float4*)(src + 4);
    *(bf16x8*)(kimg + (size_t)i * 8) = cvt8(a, bb, 1.0f);
  } else {
    // V^T tile image: 16B-block b holds vT[d=b>>4][(((b&15)*8)^swze(d))..+8]
    const int bt = bid - (514 + 4096);  // bh*64 + tile
    const float* vb = v + (size_t)bt * CHUNK * DDIM;
#pragma unroll
    for (int rep = 0; rep < 4; ++rep) {
      int e = (rep * 256 + tid) * 8;
      float4 a = *(const float4*)(vb + e);
      float4 b = *(const float4*)(vb + e + 4);
      *(bf16x8*)&t[e] = cvt8(a, b, 1.0f);
    }
    __syncthreads();
#pragma unroll
    for (int rep = 0; rep < 4; ++rep) {
      int b = rep * 256 + tid;
      int d = b >> 4;
      int y0 = ((b & 15) * 8) ^ swze(d);
      bf16x8 o8;
#pragma unroll
      for (int j = 0; j < 8; ++j) o8[j] = t[(y0 + j) * DDIM + d];
      *(bf16x8*)(vimg + (size_t)bt * 8192 + (size_t)b * 8) = o8;
    }
  }
}

// One WG = 64 q-rows, 4 waves x 16 rows, window 512 in four 128-chunks.
// r19 body + relk staged to LDS: per WG-chunk the needed relk rows form ONE
// contiguous 208-row block [B, B+208), B = 194-64rg+128c (== 2 mod 64); wave w's
// local row is l = 16*(jur-w)+c16 (rg/c-independent). rbuf is staged coalesced
// from the pre-swizzled relk2 image on the same double-stage barrier discipline
// as kbuf, turning ~20 scattered 16-line VMEM loads per wave-chunk in the QK
// critical path into conflict-free ds_read_b128.
template <bool PRECONV>
__global__ __launch_bounds__(256, 2) void attn_kernel(
    const float* __restrict__ qg, const float* __restrict__ kg, const float* __restrict__ vg,
    const __bf16* __restrict__ relk, const __bf16* __restrict__ relvT,
    const __bf16* __restrict__ relk2,
    const __bf16* __restrict__ kimg, const __bf16* __restrict__ vimg,
    float* __restrict__ outg) {
  __shared__ __align__(16) __bf16 kbuf[CHUNK * DDIM];  // 16KB K [y][d] swizzled
  __shared__ __align__(16) __bf16 vbuf[CHUNK * DDIM];  // 16KB vT [d][y] swizzled
  __shared__ __align__(16) __bf16 pbuf[64 * CHUNK];    // 16KB P [q][y], per-wave slabs
  __shared__ __align__(16) __bf16 rbuf[208 * DDIM];    // 26KB relk rows [B,B+208) swizzled
  __shared__ __bf16 ring[4][2][16][17];                // 4.25KB per-wave QR^T ring (bf16)

  const int phys = blockIdx.x;
  const int xcd = phys & 7;
  const int mseq = phys >> 3;
  const int rg = mseq & 3;
  const int gl = mseq >> 2;
  const int pair = xcd * 64 + gl;
  const int bh = pair >> 5;
  const int nblk = pair & 31;

  const int tid = threadIdx.x;
  const int w = tid >> 6;
  const int lane = tid & 63;
  const int c16 = lane & 15;
  const int grp = lane >> 4;

  const int row_base = rg * 64 + 16 * w;
  const int c0w = 194 - row_base;
  const int j0w = 192 - row_base;
  const int prow = 16 * w + c16;

  const int cstart = (nblk == 0) ? 2 : 0;
  const int c_hi = (rg >= 2) ? 4 : 3;

  auto stage_k = [&](int c) {
    if constexpr (PRECONV) {
      const __bf16* base = kimg + (((size_t)bh * 64 + (size_t)(2 * nblk - 2 + c)) << 13);
      const int boff = 256 * w;
#pragma unroll
      for (int rep = 0; rep < 4; ++rep)
        gload16(base + (size_t)(boff + 64 * rep + lane) * 8, &kbuf[(boff + 64 * rep) * 8]);
    } else {
      const int ty = tid >> 3, td = tid & 7, d0 = td * 8;
      const float* kb = kg + ((size_t)bh * LSEQ + (size_t)(2 * nblk - 2 + c) * CHUNK) * DDIM;
#pragma unroll
      for (int rep = 0; rep < 4; ++rep) {
        int yc = ty + rep * 32;
        const float4* sp = (const float4*)(kb + yc * DDIM + d0);
        *(bf16x8*)&kbuf[yc * 64 + (d0 ^ swze(yc))] = cvt8(sp[0], sp[1], 1.0f);
      }
    }
  };
  auto stage_v = [&](int c) {
    if constexpr (PRECONV) {
      const __bf16* base = vimg + (((size_t)bh * 64 + (size_t)(2 * nblk - 2 + c)) << 13);
      const int boff = 256 * w;
#pragma unroll
      for (int rep = 0; rep < 4; ++rep)
        gload16(base + (size_t)(boff + 64 * rep + lane) * 8, &vbuf[(boff + 64 * rep) * 8]);
    } else {
      const int ty = tid >> 3, td = tid & 7, d0 = td * 8;
      const float* vb = vg + ((size_t)bh * LSEQ + (size_t)(2 * nblk - 2 + c) * CHUNK) * DDIM;
#pragma unroll
      for (int rep = 0; rep < 4; ++rep) {
        int yc = ty + rep * 32;
        const float4* sp = (const float4*)(vb + yc * DDIM + d0);
        float ff[8] = {sp[0].x, sp[0].y, sp[0].z, sp[0].w, sp[1].x, sp[1].y, sp[1].z, sp[1].w};
#pragma unroll
        for (int i = 0; i < 8; ++i) {
          int d = d0 + i;
          vbuf[d * CHUNK + (yc ^ swze(d))] = (__bf16)ff[i];
        }
      }
    }
  };
  // stage relk rows [B, B+208) for chunk c; source pre-swizzled so linear
  // gload16 lands rbuf[l][sc ^ swze(l)] (B == 2 mod 64 guarantees alignment).
  auto stage_r = [&](int c) {
    if constexpr (PRECONV) {
      const __bf16* src = relk2 + (size_t)(194 - 64 * rg + 128 * c) * DDIM;
#pragma unroll
      for (int rep = 0; rep < 7; ++rep) {
        int b = rep * 256 + tid;  // 16B-block index, need [0,1664)
        if (b < 1664) gload16(src + (size_t)b * 8, &rbuf[b * 8]);
      }
    }
  };

  // q fragment: Q[q=row_base+c16][d=32*kk+8*grp+i], scaled by D^-0.5 * log2(e)
  bf16x8 qa[2];
  {
    const float* qrow = qg + (size_t)(bh * LSEQ + nblk * QS + row_base + c16) * DDIM;
#pragma unroll
    for (int kk = 0; kk < 2; ++kk) {
      const float4* sp = (const float4*)(qrow + kk * 32 + grp * 8);
      qa[kk] = cvt8(sp[0], sp[1], QSCALE);
    }
  }

  f32x4 o[4];  // o[jd][r] = O[q=4*grp+r][d=16*jd+c16]
#pragma unroll
  for (int jd = 0; jd < 4; ++jd) o[jd] = f32x4{0.f, 0.f, 0.f, 0.f};
  float lsum = 0.f;

  // QR^T tile B-operand loads (jur = ju - 8c; rbuf local row l = 16*(jur-w)+c16)
  auto qr_load = [&](int ju, int jur, bf16x8& b0, bf16x8& b1) {
    if constexpr (PRECONV) {
      int l = 16 * (jur - w) + c16;
      int sw = swze(l);
      b0 = *(const bf16x8*)&rbuf[l * 64 + ((8 * grp) ^ sw)];
      b1 = *(const bf16x8*)&rbuf[l * 64 + ((32 + 8 * grp) ^ sw)];
    } else {
      int t = c0w + 16 * ju + c16;
      b0 = *(const bf16x8*)(relk + t * DDIM + 8 * grp);
      b1 = *(const bf16x8*)(relk + t * DDIM + 32 + 8 * grp);
    }
  };
  auto qr_tile = [&](int ju, int jur) {  // prologue: immediate ring write
    f32x4 acc = {0.f, 0.f, 0.f, 0.f};
    bf16x8 b0, b1;
    qr_load(ju, jur, b0, b1);
    acc = mfma16(b0, qa[0], acc);
    acc = mfma16(b1, qa[1], acc);
#pragma unroll
    for (int r = 0; r < 4; ++r) ring[w][ju & 1][4 * grp + r][c16] = (__bf16)acc[r];
  };

  stage_k(cstart);
  stage_r(cstart);
  __syncthreads();  // kbuf/rbuf(cstart) resident

  for (int c = cstart; c < c_hi; ++c) {
    int jtl_hi = 4 * rg + w + 17 - 8 * c;     // wave-uniform valid-tile bound
    jtl_hi = jtl_hi < 0 ? 0 : (jtl_hi > 8 ? 8 : jtl_hi);
    const bool active = jtl_hi > 0;

    stage_v(c);  // async into vbuf; hidden under QK

    if (active) {
      if (c == cstart) {  // later chunks inherit 8c+3/8c+4 from chunk c-1's jtl 6/7
        qr_tile(8 * c + 3, 3);
        qr_tile(8 * c + 4, 4);
      }
      float ps = 0.f;
#pragma unroll
      for (int jtl = 0; jtl < 8; ++jtl) {
        if (jtl < jtl_hi) {  // wave-uniform: skip fully-masked tail tiles
          const int jt = 8 * c + jtl;
          // phase 1: QR tile jt+5 into registers (ring write deferred)
          f32x4 qacc = {0.f, 0.f, 0.f, 0.f};
          {
            bf16x8 b0, b1;
            qr_load(jt + 5, jtl + 5, b0, b1);
            qacc = mfma16(b0, qa[0], qacc);
            qacc = mfma16(b1, qa[1], qacc);
          }
          // phase 2: QK
          f32x4 acc = {-SMAX, -SMAX, -SMAX, -SMAX};
          int krow = 16 * jtl + c16;
          const bf16x8 aK0 = *(const bf16x8*)&kbuf[krow * 64 + ((8 * grp) ^ swze(krow))];
          const bf16x8 aK1 = *(const bf16x8*)&kbuf[krow * 64 + ((32 + 8 * grp) ^ swze(krow))];
          acc = mfma16(aK0, qa[0], acc);
          acc = mfma16(aK1, qa[1], acc);
          // phase 3: ring reads (tiles jt+3/jt+4, written >=1 jtl ago) + exp + P store
          bf16x4 pw;
#pragma unroll
          for (int r = 0; r < 4; ++r) {
            int sk = 4 * grp + r + 15 - c16;
            float qrv = (float)ring[w][(jt + 3 + (sk >> 4)) & 1][sk & 15][c16];
            int yv = 16 * jt + 4 * grp + r;
            float arg = (yv <= row_base + c16 + 256) ? (acc[r] + qrv) : -1e9f;
            float pv = fexp2(arg);
            ps += pv;
            pw[r] = (__bf16)pv;
          }
          *(bf16x4*)&pbuf[prow * CHUNK + ((16 * jtl + 4 * grp) ^ swze(prow))] = pw;
          // phase 4: deferred ring write of jt+5
#pragma unroll
          for (int r = 0; r < 4; ++r) ring[w][(jt + 5) & 1][4 * grp + r][c16] = (__bf16)qacc[r];
        }
      }
      // odd jtl_hi -> PV's ks block [jtl_hi-1, jtl_hi] reads P tile jtl_hi,
      // which the guarded loop no longer writes. Zero-fill that one tile.
      if (jtl_hi < 8 && (jtl_hi & 1)) {
        bf16x4 z = {};
        *(bf16x4*)&pbuf[prow * CHUNK + ((16 * jtl_hi + 4 * grp) ^ swze(prow))] = z;
      }
      lsum += ps;
    }

    __syncthreads();  // vbuf(c) resident; kbuf/rbuf reads done

    if (c + 1 < c_hi) {  // async into kbuf/rbuf; hidden under PV
      stage_k(c + 1);
      stage_r(c + 1);
    }

    if (active) {
      const int ks_hi = (jtl_hi + 1) >> 1;          // P tiles beyond are never read
      int s2_hi = (16 * jtl_hi + 62) >> 5;
      s2_hi = s2_hi > 5 ? 5 : s2_hi;
      const int ylim = 16 * jtl_hi;                  // <= CHUNK
      __builtin_amdgcn_s_setprio(1);
#pragma unroll
      for (int ks = 0; ks < 4; ++ks) {
        if (ks < ks_hi) {
          bf16x8 aP = *(const bf16x8*)&pbuf[prow * CHUNK + ((32 * ks + 8 * grp) ^ swze(prow))];
#pragma unroll
          for (int jd = 0; jd < 4; ++jd) {
            int drow = 16 * jd + c16;
            bf16x8 bV = *(const bf16x8*)&vbuf[drow * CHUNK + ((32 * ks + 8 * grp) ^ swze(drow))];
            o[jd] = mfma16(aP, bV, o[jd]);
          }
        }
      }
#pragma unroll
      for (int s2 = 0; s2 < 5; ++s2) {
        if (s2 < s2_hi) {
          bf16x8 aW;
#pragma unroll
          for (int i = 0; i < 8; ++i) {
            int yl = 32 * s2 + 8 * grp + i + c16 - 31;
            __bf16 pv = (__bf16)0.f;
            if (yl >= 0 && yl < ylim) pv = pbuf[prow * CHUNK + (yl ^ swze(prow))];
            aW[i] = pv;
          }
          const int u0 = 128 * c + 32 + 32 * s2 + 8 * grp;
#pragma unroll
          for (int jd = 0; jd < 4; ++jd) {
            int d = 16 * jd + c16;
            const bf16x8* bR = (const bf16x8*)(relvT + d * RELVT_PITCH + j0w + u0);
            o[jd] = mfma16(aW, *bR, o[jd]);
          }
        }
      }
      __builtin_amdgcn_s_setprio(0);
    }

    __syncthreads();  // own K/R(c+1) drained; vbuf/pbuf reads done
  }

  // ---- epilogue: lsum reduce, normalize, store ----
  lsum += __shfl_xor(lsum, 16);
  lsum += __shfl_xor(lsum, 32);
  float inv = 1.0f / lsum;  // lane c16 holds q-row c16's inverse sum
  float* ob = outg + (size_t)(bh * LSEQ + nblk * QS + row_base) * DDIM;
#pragma unroll
  for (int r = 0; r < 4; ++r) {
    float ir = __shfl(inv, 4 * grp + r);
#pragma unroll
    for (int jd = 0; jd < 4; ++jd) {
      ob[(4 * grp + r) * DDIM + 16 * jd + c16] = o[jd][r] * ir;
    }
  }
}

extern "C" void kernel_launch(void* const* d_in, const int* in_sizes, int n_in,
                              void* d_out, int out_size, void* d_ws, size_t ws_size,
                              hipStream_t stream) {
  const float* q = (const float*)d_in[0];
  const float* k = (const float*)d_in[1];
  const float* v = (const float*)d_in[2];
  const float* rk = (const float*)d_in[3];
  const float* rv = (const float*)d_in[4];

  char* ws = (char*)d_ws;
  __bf16* relk = (__bf16*)(ws + WS_RELK_OFF);
  __bf16* relvT = (__bf16*)(ws + WS_RELVT_OFF);
  __bf16* relk2 = (__bf16*)(ws + WS_RELK2_OFF);
  __bf16* kimg = (__bf16*)(ws + WS_KIMG_OFF);
  __bf16* vimg = (__bf16*)(ws + WS_VIMG_OFF);

  if (ws_size >= WS_NEED) {
    prep_all<<<514 + 4096 + 1024, 256, 0, stream>>>(rk, rv, k, v, relk, relvT, relk2, kimg, vimg);
    attn_kernel<true><<<2048, 256, 0, stream>>>(q, k, v, relk, relvT, relk2, kimg, vimg,
                                                (float*)d_out);
  } else {
    prep_all<<<257, 256, 0, stream>>>(rk, rv, k, v, relk, relvT, relk, relk, relk);
    attn_kernel<false><<<2048, 256, 0, stream>>>(q, k, v, relk, relvT, relk, relk, relk,
                                                 (float*)d_out);
  }
}